// Round 19
// baseline (177.373 us; speedup 1.0000x reference)
//
#include <hip/hip_runtime.h>
#include <math.h>

#define N_NODES 100000
#define N_EDGES 3200000
#define BSHIFT 6
#define NBUCK 1563           // ceil(100000/64) coarse buckets (src>>6)
#define NBLK_E 256           // edge-pass blocks
#define EPB 12500            // edges per edge-pass block (256*12500 = 3.2M exactly)
#define CAP 3072             // max edges per 64-node bucket (mean 2048, sd ~45)
#define BM 96                // MLP row-tile
#define MLP_BLOCKS ((N_NODES + BM - 1) / BM)   // 1042
#define PREP_TOTAL (N_NODES * 32 + 128 * 256 + 2 * 256 * 256)   // 3,363,840
#define PREP_PER_BLK ((PREP_TOTAL + NBLK_E - 1) / NBLK_E)       // 13,140

typedef _Float16 half8 __attribute__((ext_vector_type(8)));
typedef float f32x4 __attribute__((ext_vector_type(4)));
typedef float f32x2 __attribute__((ext_vector_type(2)));

__device__ __forceinline__ void gload16(const void* gsrc, void* ldst) {
    __builtin_amdgcn_global_load_lds(
        (const __attribute__((address_space(1))) unsigned int*)gsrc,
        (__attribute__((address_space(3))) unsigned int*)ldst,
        16, 0, 0);
}

// ---------------------------------------------------------------------------
// K0: prep (pack fp8 feats + weight transpose) + coarse histogram, merged.
// BW-bound prep slice and latency-bound LDS-atomic hist interleave per block.
// ---------------------------------------------------------------------------
__global__ __launch_bounds__(1024) void prep_hist_kernel(
    const float* __restrict__ x, const float* __restrict__ pos,
    const float* __restrict__ z, unsigned int* __restrict__ feats8,
    const float* __restrict__ W1, _Float16* __restrict__ WT1,
    const float* __restrict__ W2, _Float16* __restrict__ WT2,
    const float* __restrict__ W3, _Float16* __restrict__ WT3,
    const int* __restrict__ ei, int* __restrict__ gcnt)
{
    __shared__ int bins[NBUCK];
    int t = threadIdx.x, blk = blockIdx.x;
    for (int b = t; b < NBUCK; b += 1024) bins[b] = 0;
    __syncthreads();

    // --- prep slice ---
    int pend = blk * PREP_PER_BLK + PREP_PER_BLK;
    if (pend > PREP_TOTAL) pend = PREP_TOTAL;
    for (int idx = blk * PREP_PER_BLK + t; idx < pend; idx += 1024) {
        if (idx < N_NODES * 32) {
            int n = idx >> 5, j = idx & 31;
            float v[4];
            #pragma unroll
            for (int k = 0; k < 4; ++k) {
                int f = j * 4 + k;
                if (f < 124)      v[k] = x[n * 124 + f];
                else if (f < 127) v[k] = pos[n * 3 + (f - 124)];
                else              v[k] = z[n];
            }
            int u = 0;
            u = __builtin_amdgcn_cvt_pk_fp8_f32(v[0], v[1], u, false);
            u = __builtin_amdgcn_cvt_pk_fp8_f32(v[2], v[3], u, true);
            feats8[idx] = (unsigned int)u;
        } else {
            int i2 = idx - N_NODES * 32;
            if (i2 < 128 * 256) {
                int k = i2 >> 8, c = i2 & 255;
                WT1[c * 128 + k] = (_Float16)W1[i2];
            } else if (i2 < 128 * 256 + 256 * 256) {
                int i = i2 - 128 * 256;
                int k = i >> 8, c = i & 255;
                WT2[c * 256 + k] = (_Float16)W2[i];
            } else {
                int i = i2 - 128 * 256 - 256 * 256;
                int k = i >> 8, c = i & 255;
                WT3[c * 256 + k] = (_Float16)W3[i];
            }
        }
    }

    // --- histogram slice ---
    int base = blk * EPB;
    for (int i = t; i < EPB; i += 1024) {
        int src = __builtin_nontemporal_load(&ei[base + i]);
        atomicAdd(&bins[src >> BSHIFT], 1);
    }
    __syncthreads();
    for (int b = t; b < NBUCK; b += 1024)
        gcnt[blk * NBUCK + b] = bins[b];
}

// ---------------------------------------------------------------------------
// K2a: per-bucket totals (column sums of gcnt)
// ---------------------------------------------------------------------------
__global__ __launch_bounds__(256) void bucket_tot_kernel(
    const int* __restrict__ gcnt, int* __restrict__ btot)
{
    __shared__ int red[4];
    int b = blockIdx.x, t = threadIdx.x;
    int s = gcnt[t * NBUCK + b];
    #pragma unroll
    for (int off = 32; off > 0; off >>= 1) s += __shfl_xor(s, off, 64);
    if ((t & 63) == 0) red[t >> 6] = s;
    __syncthreads();
    if (t == 0) btot[b] = red[0] + red[1] + red[2] + red[3];
}

// ---------------------------------------------------------------------------
// K2b: exclusive scan of 1563 bucket totals -> bbase[0..NBUCK]
// ---------------------------------------------------------------------------
__global__ __launch_bounds__(1024) void scan_buckets_kernel(
    const int* __restrict__ btot, int* __restrict__ bbase)
{
    __shared__ int s[1024];
    int t = threadIdx.x;
    int i0 = 2 * t, i1 = 2 * t + 1;
    int v0 = (i0 < NBUCK) ? btot[i0] : 0;
    int v1 = (i1 < NBUCK) ? btot[i1] : 0;
    int sum = v0 + v1;
    s[t] = sum;
    __syncthreads();
    for (int off = 1; off < 1024; off <<= 1) {
        int o = (t >= off) ? s[t - off] : 0;
        __syncthreads();
        s[t] += o;
        __syncthreads();
    }
    int excl = s[t] - sum;
    if (i0 < NBUCK) bbase[i0] = excl;
    if (i1 < NBUCK) bbase[i1] = excl + v0;
    if (i0 == NBUCK - 1) bbase[NBUCK] = excl + v0;
    if (i1 == NBUCK - 1) bbase[NBUCK] = excl + v0 + v1;
}

// ---------------------------------------------------------------------------
// K2c: per-bucket column scan over blocks
// ---------------------------------------------------------------------------
__global__ __launch_bounds__(256) void colscan_kernel(
    const int* __restrict__ gcnt, const int* __restrict__ bbase,
    int* __restrict__ gbase)
{
    __shared__ int s[NBLK_E];
    int b = blockIdx.x, t = threadIdx.x;
    int v = gcnt[t * NBUCK + b];
    s[t] = v;
    __syncthreads();
    for (int off = 1; off < NBLK_E; off <<= 1) {
        int o = (t >= off) ? s[t - off] : 0;
        __syncthreads();
        s[t] += o;
        __syncthreads();
    }
    gbase[t * NBUCK + b] = bbase[b] + s[t] - v;
}

// ---------------------------------------------------------------------------
// K3: bucket scatter via block-local LDS counting sort + ordered write-out.
// gd[] removed: phase C recovers the bucket of position i by binary search
// over cur[] (post-phase-B = local upper bounds). LDS 67 KB -> 2 blocks/CU.
// ---------------------------------------------------------------------------
__global__ __launch_bounds__(1024) void bucket_scatter_kernel(
    const int* __restrict__ ei, const int* __restrict__ gcnt,
    const int* __restrict__ gbase, unsigned int* __restrict__ bucketed)
{
    __shared__ unsigned int val[EPB];    // 50 KB
    __shared__ int cur[NBUCK];           // 6.25 KB
    __shared__ int gofs[NBUCK];          // 6.25 KB
    __shared__ int ssum[1024];           // 4 KB

    int t = threadIdx.x, blk = blockIdx.x;

    // Phase A: local exclusive scan of block's 1563 bin counts
    int i0 = 2 * t, i1 = 2 * t + 1;
    int c0 = (i0 < NBUCK) ? gcnt[blk * NBUCK + i0] : 0;
    int c1 = (i1 < NBUCK) ? gcnt[blk * NBUCK + i1] : 0;
    int sum = c0 + c1;
    ssum[t] = sum;
    __syncthreads();
    for (int off = 1; off < 1024; off <<= 1) {
        int o = (t >= off) ? ssum[t - off] : 0;
        __syncthreads();
        ssum[t] += o;
        __syncthreads();
    }
    int excl = ssum[t] - sum;
    if (i0 < NBUCK) { cur[i0] = excl;      gofs[i0] = gbase[blk * NBUCK + i0] - excl; }
    if (i1 < NBUCK) { cur[i1] = excl + c0; gofs[i1] = gbase[blk * NBUCK + i1] - (excl + c0); }
    __syncthreads();

    // Phase B: rank + stash into LDS (local counting sort)
    int base = blk * EPB;
    for (int i = t; i < EPB; i += 1024) {
        int e = base + i;
        int src = __builtin_nontemporal_load(&ei[e]);
        int dst = __builtin_nontemporal_load(&ei[N_EDGES + e]);
        int b = src >> BSHIFT;
        int r = atomicAdd(&cur[b], 1);                 // local sorted position
        val[r] = (unsigned int)dst | ((unsigned int)(src & 63) << 17);
    }
    __syncthreads();
    // now cur[b] = local end offset = excl[b+1] (contiguous) -> upper bounds

    // Phase C: ordered write-out; bucket of i via binary search on cur[]
    for (int i = t; i < EPB; i += 1024) {
        int lo = 0, hi = NBUCK - 1;
        while (lo < hi) {
            int mid = (lo + hi) >> 1;
            if (cur[mid] > i) hi = mid; else lo = mid + 1;
        }
        bucketed[gofs[lo] + i] = val[i];
    }
}

// ---------------------------------------------------------------------------
// K4: per-bucket LDS counting sort + fp8 gather-aggregate + L2 normalize
// -> h0 (f16).  16-lane row groups: lane loads uint2 (8 fp8), wave does
// 4 edges at once, 24-edge main loop (6 uint2 in flight per lane).
// ---------------------------------------------------------------------------
__global__ __launch_bounds__(256) void sortagg_kernel(
    const int* __restrict__ bbase, const unsigned int* __restrict__ bucketed,
    const uint2* __restrict__ feats8u2, _Float16* __restrict__ h0)
{
    __shared__ unsigned int srt[CAP];
    __shared__ int excl[64], cur[64];

    int t = threadIdx.x, b = blockIdx.x;
    int segs = bbase[b], cnt = bbase[b + 1] - segs;
    if (cnt > CAP) cnt = CAP;   // statistically never (slack ~22 sd)

    if (t < 64) cur[t] = 0;
    __syncthreads();

    // phase 1: fine histogram
    for (int i = t; i < cnt; i += 256)
        atomicAdd(&cur[(bucketed[segs + i] >> 17) & 63], 1);
    __syncthreads();

    // phase 2: scan 64 bins
    int v = (t < 64) ? cur[t] : 0;
    if (t < 64) excl[t] = v;
    __syncthreads();
    for (int off = 1; off < 64; off <<= 1) {
        int o = (t >= off && t < 64) ? excl[t - off] : 0;
        __syncthreads();
        if (t < 64) excl[t] += o;
        __syncthreads();
    }
    if (t < 64) { excl[t] -= v; cur[t] = excl[t]; }
    __syncthreads();

    // phase 3: counting-sort into srt
    for (int i = t; i < cnt; i += 256) {
        unsigned int p = bucketed[segs + i];
        int r = atomicAdd(&cur[(p >> 17) & 63], 1);
        if (r < CAP) srt[r] = p & 0x1FFFFu;
    }
    __syncthreads();

    // phase 4: aggregate per node (wave w owns nodes w*16 .. w*16+15)
    int w = t >> 6, lane = t & 63;
    int h = lane >> 4;         // edge group 0..3
    int s = lane & 15;         // feats 8s..8s+7
    const uint2* fb = feats8u2 + s;

#define ACC8(U)                                                     \
    a01 += __builtin_amdgcn_cvt_pk_f32_fp8((U).x, false);           \
    a23 += __builtin_amdgcn_cvt_pk_f32_fp8((U).x, true);            \
    a45 += __builtin_amdgcn_cvt_pk_f32_fp8((U).y, false);           \
    a67 += __builtin_amdgcn_cvt_pk_f32_fp8((U).y, true);

    for (int j = 0; j < 16; ++j) {
        int nl = w * 16 + j;
        int node = b * 64 + nl;
        if (node >= N_NODES) break;
        int start = excl[nl], end = cur[nl];
        f32x2 a01 = {0.f, 0.f}, a23 = {0.f, 0.f};
        f32x2 a45 = {0.f, 0.f}, a67 = {0.f, 0.f};
        int i = start;
        for (; i + 24 <= end; i += 24) {
            uint2 uu[6];
            #pragma unroll
            for (int q = 0; q < 6; ++q)
                uu[q] = fb[(long long)srt[i + 4 * q + h] * 16];
            #pragma unroll
            for (int q = 0; q < 6; ++q) { ACC8(uu[q]); }
        }
        for (; i + 4 <= end; i += 4) {
            uint2 u = fb[(long long)srt[i + h] * 16];
            ACC8(u);
        }
        if (i + h < end) {
            uint2 u = fb[(long long)srt[i + h] * 16];
            ACC8(u);
        }
        // merge across the 4 edge-groups (lanes differing in bits 4,5)
#define MRG(A)                                                      \
        A[0] += __shfl_xor(A[0], 16, 64);                           \
        A[1] += __shfl_xor(A[1], 16, 64);                           \
        A[0] += __shfl_xor(A[0], 32, 64);                           \
        A[1] += __shfl_xor(A[1], 32, 64);
        MRG(a01) MRG(a23) MRG(a45) MRG(a67)
#undef MRG
        float ss = a01[0]*a01[0] + a01[1]*a01[1] + a23[0]*a23[0] + a23[1]*a23[1]
                 + a45[0]*a45[0] + a45[1]*a45[1] + a67[0]*a67[0] + a67[1]*a67[1];
        #pragma unroll
        for (int off = 8; off > 0; off >>= 1) ss += __shfl_xor(ss, off, 64);
        float inv = 1.0f / sqrtf(ss);
        if (h == 0) {
            union { uint4 u; _Float16 f[8]; } o;
            o.f[0] = (_Float16)(a01[0] * inv); o.f[1] = (_Float16)(a01[1] * inv);
            o.f[2] = (_Float16)(a23[0] * inv); o.f[3] = (_Float16)(a23[1] * inv);
            o.f[4] = (_Float16)(a45[0] * inv); o.f[5] = (_Float16)(a45[1] * inv);
            o.f[6] = (_Float16)(a67[0] * inv); o.f[7] = (_Float16)(a67[1] * inv);
            *reinterpret_cast<uint4*>(&h0[(long long)node * 128 + s * 8]) = o.u;
        }
    }
#undef ACC8
}

// ---------------------------------------------------------------------------
// K5: FUSED MLP, BM=96, double-buffered sB, counted-vmcnt pipeline.
// ---------------------------------------------------------------------------
__global__ __launch_bounds__(256, 2) void fused_mlp_kernel(
    const _Float16* __restrict__ h0,    // [M][128]
    const _Float16* __restrict__ WT1,   // [256][128]
    const float* __restrict__ b1,
    const _Float16* __restrict__ WT2,   // [256][256]
    const float* __restrict__ b2,
    const _Float16* __restrict__ WT3,   // [256][256]
    const float* __restrict__ b3,
    const float* __restrict__ W4,       // [256]
    float* __restrict__ partials, int M)
{
    __shared__ __align__(16) _Float16 sA[8 * 3072];      // 48 KB (8 chunks 96x32)
    __shared__ __align__(16) _Float16 sB[2][8192];       // 2 x 16 KB

    const int t = threadIdx.x;
    const int row0 = blockIdx.x * BM;

    const int ap0 = t & 3;
    const int r0 = t >> 2;
    const int ag0 = ap0 ^ ((r0 >> 1) & 3);
    int arow0 = row0 + r0; if (arow0 > M - 1) arow0 = M - 1;
    const _Float16* aSrc0 = h0 + (long long)arow0 * 128 + ag0 * 8;
    const int r1 = (256 + t) >> 2;
    const int ag1 = ap0 ^ ((r1 >> 1) & 3);
    int arow1 = row0 + r1; if (arow1 > M - 1) arow1 = M - 1;
    const _Float16* aSrc1 = h0 + (long long)arow1 * 128 + ag1 * 8;

    const int bc0 = t >> 2;
    const int gb = ap0 ^ ((bc0 >> 1) & 3);

    const int w = t >> 6, lane = t & 63;
    const int wr = w >> 1, wc = w & 1;
    const int lrow = lane & 15, g = lane >> 4;

    unsigned int offA[3], offB[8];
    #pragma unroll
    for (int rt = 0; rt < 3; ++rt) {
        int r = wr * 48 + rt * 16 + lrow;
        offA[rt] = r * 64 + (g ^ ((r >> 1) & 3)) * 16;
    }
    #pragma unroll
    for (int ct = 0; ct < 8; ++ct) {
        int cidx = wc * 128 + ct * 16 + lrow;
        offB[ct] = cidx * 64 + (g ^ ((cidx >> 1) & 3)) * 16;
    }

    float bb1[8], bb2[8], bb3[8], w4v[8];
    #pragma unroll
    for (int ct = 0; ct < 8; ++ct) {
        int col = wc * 128 + ct * 16 + lrow;
        bb1[ct] = b1[col]; bb2[ct] = b2[col];
        bb3[ct] = b3[col]; w4v[ct] = W4[col];
    }

    f32x4 acc[3][8];
    #pragma unroll
    for (int i = 0; i < 3; ++i)
        #pragma unroll
        for (int j = 0; j < 8; ++j)
            acc[i][j] = (f32x4){0.f, 0.f, 0.f, 0.f};

#define STG(WT, Kv, KC, BUF)                                                 \
    {                                                                        \
        _Pragma("unroll")                                                    \
        for (int j = 0; j < 4; ++j)                                          \
            gload16((WT) + (long long)(bc0 + j * 64) * (Kv) + gb * 8 +       \
                        (KC) * 32,                                           \
                    (char*)sB[BUF] + j * 4096 + t * 16);                     \
    }

#define WB(N)                                                                \
    asm volatile("s_waitcnt vmcnt(" #N ")" ::: "memory");                    \
    __builtin_amdgcn_s_barrier();                                            \
    __builtin_amdgcn_sched_barrier(0);

#define EB() __builtin_amdgcn_s_barrier();

#define SEAM()                                                               \
    asm volatile("s_waitcnt lgkmcnt(0)" ::: "memory");                       \
    __builtin_amdgcn_s_barrier();                                            \
    __builtin_amdgcn_sched_barrier(0);

#define STORE_ACTS(BB)                                                       \
    {                                                                        \
        _Pragma("unroll")                                                    \
        for (int ct = 0; ct < 8; ++ct) {                                     \
            int col = wc * 128 + ct * 16 + lrow;                             \
            float bb = (BB)[ct];                                             \
            int chk = col >> 5, kk = col & 31;                               \
            int kg = kk >> 3, ke = kk & 7;                                   \
            _Pragma("unroll")                                                \
            for (int rt = 0; rt < 3; ++rt) {                                 \
                _Pragma("unroll")                                            \
                for (int jj = 0; jj < 4; ++jj) {                             \
                    int rowl = wr * 48 + rt * 16 + g * 4 + jj;               \
                    int slot = kg ^ ((rowl >> 1) & 3);                       \
                    sA[chk * 3072 + rowl * 32 + slot * 8 + ke] =             \
                        (_Float16)fmaxf(acc[rt][ct][jj] + bb, 0.f);          \
                    acc[rt][ct][jj] = 0.f;                                   \
                }                                                            \
            }                                                                \
        }                                                                    \
    }

#define MFMA_CHUNK(KC, BUF)                                                  \
    {                                                                        \
        half8 a[3], bfr[8];                                                  \
        __builtin_amdgcn_s_setprio(1);                                       \
        _Pragma("unroll")                                                    \
        for (int rt = 0; rt < 3; ++rt)                                       \
            a[rt] = *reinterpret_cast<const half8*>(                         \
                (const char*)sA + (KC) * 6144 + offA[rt]);                   \
        _Pragma("unroll")                                                    \
        for (int ct = 0; ct < 8; ++ct)                                       \
            bfr[ct] = *reinterpret_cast<const half8*>(                       \
                (const char*)sB[BUF] + offB[ct]);                            \
        _Pragma("unroll")                                                    \
        for (int rt = 0; rt < 3; ++rt)                                       \
            _Pragma("unroll")                                                \
            for (int ct = 0; ct < 8; ++ct)                                   \
                acc[rt][ct] = __builtin_amdgcn_mfma_f32_16x16x32_f16(        \
                    a[rt], bfr[ct], acc[rt][ct], 0, 0, 0);                   \
        __builtin_amdgcn_s_setprio(0);                                       \
    }

    // prologue: layer-1 A chunks (96x128 f16 = 6 KB/chunk) + B chunk 0
    #pragma unroll
    for (int kc = 0; kc < 4; ++kc) {
        gload16(aSrc0 + kc * 32, (char*)sA + kc * 6144 + t * 16);
        if (t < 128)
            gload16(aSrc1 + kc * 32, (char*)sA + kc * 6144 + 4096 + t * 16);
    }
    STG(WT1, 128, 0, 0)

    // ---- pipelined chunk schedule (c = 0..19, buf = c&1) ----
    STG(WT1, 128, 1, 1)  WB(4)  MFMA_CHUNK(0, 0)  EB()   // c=0
    STG(WT1, 128, 2, 0)  WB(4)  MFMA_CHUNK(1, 1)  EB()   // c=1
    STG(WT1, 128, 3, 1)  WB(4)  MFMA_CHUNK(2, 0)  EB()   // c=2
    STG(WT2, 256, 0, 0)  WB(4)  MFMA_CHUNK(3, 1)  EB()   // c=3
    STORE_ACTS(bb1) SEAM()
    STG(WT2, 256, 1, 1)  WB(4)  MFMA_CHUNK(0, 0)  EB()   // c=4
    STG(WT2, 256, 2, 0)  WB(4)  MFMA_CHUNK(1, 1)  EB()   // c=5
    STG(WT2, 256, 3, 1)  WB(4)  MFMA_CHUNK(2, 0)  EB()   // c=6
    STG(WT2, 256, 4, 0)  WB(4)  MFMA_CHUNK(3, 1)  EB()   // c=7
    STG(WT2, 256, 5, 1)  WB(4)  MFMA_CHUNK(4, 0)  EB()   // c=8
    STG(WT2, 256, 6, 0)  WB(4)  MFMA_CHUNK(5, 1)  EB()   // c=9
    STG(WT2, 256, 7, 1)  WB(4)  MFMA_CHUNK(6, 0)  EB()   // c=10
    STG(WT3, 256, 0, 0)  WB(4)  MFMA_CHUNK(7, 1)  EB()   // c=11
    STORE_ACTS(bb2) SEAM()
    STG(WT3, 256, 1, 1)  WB(4)  MFMA_CHUNK(0, 0)  EB()   // c=12
    STG(WT3, 256, 2, 0)  WB(4)  MFMA_CHUNK(1, 1)  EB()   // c=13
    STG(WT3, 256, 3, 1)  WB(4)  MFMA_CHUNK(2, 0)  EB()   // c=14
    STG(WT3, 256, 4, 0)  WB(4)  MFMA_CHUNK(3, 1)  EB()   // c=15
    STG(WT3, 256, 5, 1)  WB(4)  MFMA_CHUNK(4, 0)  EB()   // c=16
    STG(WT3, 256, 6, 0)  WB(4)  MFMA_CHUNK(5, 1)  EB()   // c=17
    STG(WT3, 256, 7, 1)  WB(4)  MFMA_CHUNK(6, 0)  EB()   // c=18
                         WB(0)  MFMA_CHUNK(7, 1)  EB()   // c=19

    // epilogue: bias+relu, dot W4, block reduce (redf aliases sA, now dead)
    float sum = 0.f;
    #pragma unroll
    for (int ct = 0; ct < 8; ++ct) {
        float bb = bb3[ct];
        float w4 = w4v[ct];
        #pragma unroll
        for (int rt = 0; rt < 3; ++rt) {
            #pragma unroll
            for (int jj = 0; jj < 4; ++jj) {
                int row = row0 + wr * 48 + rt * 16 + g * 4 + jj;
                if (row < M) {
                    float vv = fmaxf(acc[rt][ct][jj] + bb, 0.f);
                    sum += vv * w4;
                }
            }
        }
    }
    #pragma unroll
    for (int off = 32; off > 0; off >>= 1) sum += __shfl_xor(sum, off, 64);
    float* redf = reinterpret_cast<float*>(sA);
    if (lane == 0) redf[w] = sum;
    __syncthreads();
    if (t == 0) partials[blockIdx.x] = redf[0] + redf[1] + redf[2] + redf[3];
#undef STG
#undef WB
#undef EB
#undef SEAM
#undef STORE_ACTS
#undef MFMA_CHUNK
}

// ---------------------------------------------------------------------------
// K6: final mean: out = sum(partials)/N + b4
// ---------------------------------------------------------------------------
__global__ __launch_bounds__(256) void final_kernel(
    const float* __restrict__ partials, int n,
    const float* __restrict__ b4, float* __restrict__ out)
{
    __shared__ float buf[256];
    float s = 0.f;
    for (int i = threadIdx.x; i < n; i += 256) s += partials[i];
    buf[threadIdx.x] = s;
    __syncthreads();
    for (int off = 128; off > 0; off >>= 1) {
        if (threadIdx.x < off) buf[threadIdx.x] += buf[threadIdx.x + off];
        __syncthreads();
    }
    if (threadIdx.x == 0) out[0] = buf[0] / (float)N_NODES + b4[0];
}

// ---------------------------------------------------------------------------
extern "C" void kernel_launch(void* const* d_in, const int* in_sizes, int n_in,
                              void* d_out, int out_size, void* d_ws, size_t ws_size,
                              hipStream_t stream)
{
    const float* x   = (const float*)d_in[0];
    const float* pos = (const float*)d_in[1];
    const float* z   = (const float*)d_in[2];
    const int*   ei  = (const int*)d_in[3];
    const float* W1  = (const float*)d_in[4];
    const float* b1  = (const float*)d_in[5];
    const float* W2  = (const float*)d_in[6];
    const float* b2  = (const float*)d_in[7];
    const float* W3  = (const float*)d_in[8];
    const float* b3  = (const float*)d_in[9];
    const float* W4  = (const float*)d_in[10];
    const float* b4  = (const float*)d_in[11];
    float* out = (float*)d_out;

    char* ws = (char*)d_ws;
    unsigned int* feats8   = (unsigned int*)(ws);              //  12,800,000
    _Float16*     h0       = (_Float16*)    (ws + 12800000);   //  25,600,000
    int*          gcnt     = (int*)         (ws + 38400000);   //   1,600,512
    int*          gbase    = (int*)         (ws + 40000512);   //   1,600,512
    int*          btot     = (int*)         (ws + 41601024);   //       6,252
    int*          bbase    = (int*)         (ws + 41607276);   //       6,256
    unsigned int* bucketed = (unsigned int*)(ws + 41613532);   //  12,800,000
    _Float16*     WT1      = (_Float16*)    (ws + 54413568);   //      65,536
    _Float16*     WT2      = (_Float16*)    (ws + 54479104);   //     131,072
    _Float16*     WT3      = (_Float16*)    (ws + 54610176);   //     131,072
    float*        partials = (float*)       (ws + 54741248);   //       6,252

    // prep (pack fp8 + weight transpose) + coarse hist, merged
    prep_hist_kernel<<<NBLK_E, 1024, 0, stream>>>(
        x, pos, z, feats8, W1, WT1, W2, WT2, W3, WT3, ei, gcnt);

    // scans
    bucket_tot_kernel<<<NBUCK, 256, 0, stream>>>(gcnt, btot);
    scan_buckets_kernel<<<1, 1024, 0, stream>>>(btot, bbase);
    colscan_kernel<<<NBUCK, 256, 0, stream>>>(gcnt, bbase, gbase);

    // bucket scatter (ordered write-out, 2 blocks/CU)
    bucket_scatter_kernel<<<NBLK_E, 1024, 0, stream>>>(ei, gcnt, gbase, bucketed);

    // per-bucket counting sort + fp8 aggregate (uint2/16-lane) -> h0 (f16)
    sortagg_kernel<<<NBUCK, 256, 0, stream>>>(
        bbase, bucketed, (const uint2*)feats8, h0);

    // fused MLP (3 layers + W4 dot), BM=96 counted-vmcnt pipeline -> partials
    fused_mlp_kernel<<<MLP_BLOCKS, 256, 0, stream>>>(
        h0, WT1, b1, WT2, b2, WT3, b3, W4, partials, N_NODES);

    // final mean
    final_kernel<<<1, 256, 0, stream>>>(partials, MLP_BLOCKS, b4, out);
}

// Round 20
// 169.759 us; speedup vs baseline: 1.0449x; 1.0449x over previous
//
#include <hip/hip_runtime.h>
#include <math.h>

#define N_NODES 100000
#define N_EDGES 3200000
#define BSHIFT 6
#define NBUCK 1563           // ceil(100000/64) coarse buckets (src>>6)
#define NBLK_E 256           // edge-pass blocks
#define EPB 12500            // edges per edge-pass block (256*12500 = 3.2M exactly)
#define CAP 3072             // max edges per 64-node bucket (mean 2048, sd ~45)
#define BM 96                // MLP row-tile
#define MLP_BLOCKS ((N_NODES + BM - 1) / BM)   // 1042

typedef _Float16 half8 __attribute__((ext_vector_type(8)));
typedef float f32x4 __attribute__((ext_vector_type(4)));
typedef float f32x2 __attribute__((ext_vector_type(2)));

__device__ __forceinline__ void gload16(const void* gsrc, void* ldst) {
    __builtin_amdgcn_global_load_lds(
        (const __attribute__((address_space(1))) unsigned int*)gsrc,
        (__attribute__((address_space(3))) unsigned int*)ldst,
        16, 0, 0);
}

// ---------------------------------------------------------------------------
// K0: prep = pack feats8 (fp8 e4m3) + weight transpose/cast (one launch)
// ---------------------------------------------------------------------------
__global__ __launch_bounds__(256) void prep_kernel(
    const float* __restrict__ x, const float* __restrict__ pos,
    const float* __restrict__ z, unsigned int* __restrict__ feats8,
    const float* __restrict__ W1, _Float16* __restrict__ WT1,
    const float* __restrict__ W2, _Float16* __restrict__ WT2,
    const float* __restrict__ W3, _Float16* __restrict__ WT3)
{
    int idx = blockIdx.x * 256 + threadIdx.x;
    if (idx < N_NODES * 32) {
        int n = idx >> 5, j = idx & 31;
        float v[4];
        #pragma unroll
        for (int k = 0; k < 4; ++k) {
            int f = j * 4 + k;
            if (f < 124)      v[k] = x[n * 124 + f];
            else if (f < 127) v[k] = pos[n * 3 + (f - 124)];
            else              v[k] = z[n];
        }
        int u = 0;
        u = __builtin_amdgcn_cvt_pk_fp8_f32(v[0], v[1], u, false);
        u = __builtin_amdgcn_cvt_pk_fp8_f32(v[2], v[3], u, true);
        feats8[idx] = (unsigned int)u;
        return;
    }
    int i2 = idx - N_NODES * 32;
    if (i2 < 128 * 256) {
        int k = i2 >> 8, c = i2 & 255;
        WT1[c * 128 + k] = (_Float16)W1[i2];
    } else if (i2 < 128 * 256 + 256 * 256) {
        int i = i2 - 128 * 256;
        int k = i >> 8, c = i & 255;
        WT2[c * 256 + k] = (_Float16)W2[i];
    } else if (i2 < 128 * 256 + 2 * 256 * 256) {
        int i = i2 - 128 * 256 - 256 * 256;
        int k = i >> 8, c = i & 255;
        WT3[c * 256 + k] = (_Float16)W3[i];
    }
}

// ---------------------------------------------------------------------------
// K1: coarse histogram per edge-block, all atomics in LDS (int = native).
// ---------------------------------------------------------------------------
__global__ __launch_bounds__(1024) void coarse_hist_kernel(
    const int* __restrict__ ei, int* __restrict__ gcnt)
{
    __shared__ int bins[NBUCK];
    int t = threadIdx.x, blk = blockIdx.x;
    for (int b = t; b < NBUCK; b += 1024) bins[b] = 0;
    __syncthreads();
    int base = blk * EPB;
    for (int i = t; i < EPB; i += 1024) {
        int src = __builtin_nontemporal_load(&ei[base + i]);
        atomicAdd(&bins[src >> BSHIFT], 1);
    }
    __syncthreads();
    for (int b = t; b < NBUCK; b += 1024)
        gcnt[blk * NBUCK + b] = bins[b];
}

// ---------------------------------------------------------------------------
// K2a: per-bucket totals (column sums of gcnt)
// ---------------------------------------------------------------------------
__global__ __launch_bounds__(256) void bucket_tot_kernel(
    const int* __restrict__ gcnt, int* __restrict__ btot)
{
    __shared__ int red[4];
    int b = blockIdx.x, t = threadIdx.x;
    int s = gcnt[t * NBUCK + b];
    #pragma unroll
    for (int off = 32; off > 0; off >>= 1) s += __shfl_xor(s, off, 64);
    if ((t & 63) == 0) red[t >> 6] = s;
    __syncthreads();
    if (t == 0) btot[b] = red[0] + red[1] + red[2] + red[3];
}

// ---------------------------------------------------------------------------
// K2b: exclusive scan of 1563 bucket totals -> bbase[0..NBUCK]
// ---------------------------------------------------------------------------
__global__ __launch_bounds__(1024) void scan_buckets_kernel(
    const int* __restrict__ btot, int* __restrict__ bbase)
{
    __shared__ int s[1024];
    int t = threadIdx.x;
    int i0 = 2 * t, i1 = 2 * t + 1;
    int v0 = (i0 < NBUCK) ? btot[i0] : 0;
    int v1 = (i1 < NBUCK) ? btot[i1] : 0;
    int sum = v0 + v1;
    s[t] = sum;
    __syncthreads();
    for (int off = 1; off < 1024; off <<= 1) {
        int o = (t >= off) ? s[t - off] : 0;
        __syncthreads();
        s[t] += o;
        __syncthreads();
    }
    int excl = s[t] - sum;
    if (i0 < NBUCK) bbase[i0] = excl;
    if (i1 < NBUCK) bbase[i1] = excl + v0;
    if (i0 == NBUCK - 1) bbase[NBUCK] = excl + v0;
    if (i1 == NBUCK - 1) bbase[NBUCK] = excl + v0 + v1;
}

// ---------------------------------------------------------------------------
// K2c: per-bucket column scan over blocks
// ---------------------------------------------------------------------------
__global__ __launch_bounds__(256) void colscan_kernel(
    const int* __restrict__ gcnt, const int* __restrict__ bbase,
    int* __restrict__ gbase)
{
    __shared__ int s[NBLK_E];
    int b = blockIdx.x, t = threadIdx.x;
    int v = gcnt[t * NBUCK + b];
    s[t] = v;
    __syncthreads();
    for (int off = 1; off < NBLK_E; off <<= 1) {
        int o = (t >= off) ? s[t - off] : 0;
        __syncthreads();
        s[t] += o;
        __syncthreads();
    }
    gbase[t * NBUCK + b] = bbase[b] + s[t] - v;
}

// ---------------------------------------------------------------------------
// K3: bucket scatter via block-local LDS counting sort + ordered write-out.
// ---------------------------------------------------------------------------
__global__ __launch_bounds__(1024) void bucket_scatter_kernel(
    const int* __restrict__ ei, const int* __restrict__ gcnt,
    const int* __restrict__ gbase, unsigned int* __restrict__ bucketed)
{
    __shared__ unsigned int val[EPB];
    __shared__ int gd[EPB];
    __shared__ int cur[NBUCK];
    __shared__ int gofs[NBUCK];
    __shared__ int ssum[1024];

    int t = threadIdx.x, blk = blockIdx.x;

    // Phase A: local exclusive scan of block's 1563 bin counts
    int i0 = 2 * t, i1 = 2 * t + 1;
    int c0 = (i0 < NBUCK) ? gcnt[blk * NBUCK + i0] : 0;
    int c1 = (i1 < NBUCK) ? gcnt[blk * NBUCK + i1] : 0;
    int sum = c0 + c1;
    ssum[t] = sum;
    __syncthreads();
    for (int off = 1; off < 1024; off <<= 1) {
        int o = (t >= off) ? ssum[t - off] : 0;
        __syncthreads();
        ssum[t] += o;
        __syncthreads();
    }
    int excl = ssum[t] - sum;
    if (i0 < NBUCK) { cur[i0] = excl;      gofs[i0] = gbase[blk * NBUCK + i0] - excl; }
    if (i1 < NBUCK) { cur[i1] = excl + c0; gofs[i1] = gbase[blk * NBUCK + i1] - (excl + c0); }
    __syncthreads();

    // Phase B: rank + stash into LDS (local counting sort)
    int base = blk * EPB;
    for (int i = t; i < EPB; i += 1024) {
        int e = base + i;
        int src = __builtin_nontemporal_load(&ei[e]);
        int dst = __builtin_nontemporal_load(&ei[N_EDGES + e]);
        int b = src >> BSHIFT;
        int r = atomicAdd(&cur[b], 1);                 // local sorted position
        val[r] = (unsigned int)dst | ((unsigned int)(src & 63) << 17);
        gd[r] = gofs[b] + r;                           // global position
    }
    __syncthreads();

    // Phase C: ordered write-out (plain stores -> L2 merges runs)
    for (int i = t; i < EPB; i += 1024)
        bucketed[gd[i]] = val[i];
}

// ---------------------------------------------------------------------------
// K4: per-bucket LDS counting sort + fp8 gather-aggregate + L2 normalize
// -> h0 (f16).  16-lane row groups: lane loads uint2 (8 fp8), wave does
// 4 edges at once, 24-edge main loop (6 uint2 in flight per lane).
// ---------------------------------------------------------------------------
__global__ __launch_bounds__(256) void sortagg_kernel(
    const int* __restrict__ bbase, const unsigned int* __restrict__ bucketed,
    const uint2* __restrict__ feats8u2, _Float16* __restrict__ h0)
{
    __shared__ unsigned int srt[CAP];
    __shared__ int excl[64], cur[64];

    int t = threadIdx.x, b = blockIdx.x;
    int segs = bbase[b], cnt = bbase[b + 1] - segs;
    if (cnt > CAP) cnt = CAP;   // statistically never (slack ~22 sd)

    if (t < 64) cur[t] = 0;
    __syncthreads();

    // phase 1: fine histogram
    for (int i = t; i < cnt; i += 256)
        atomicAdd(&cur[(bucketed[segs + i] >> 17) & 63], 1);
    __syncthreads();

    // phase 2: scan 64 bins
    int v = (t < 64) ? cur[t] : 0;
    if (t < 64) excl[t] = v;
    __syncthreads();
    for (int off = 1; off < 64; off <<= 1) {
        int o = (t >= off && t < 64) ? excl[t - off] : 0;
        __syncthreads();
        if (t < 64) excl[t] += o;
        __syncthreads();
    }
    if (t < 64) { excl[t] -= v; cur[t] = excl[t]; }
    __syncthreads();

    // phase 3: counting-sort into srt
    for (int i = t; i < cnt; i += 256) {
        unsigned int p = bucketed[segs + i];
        int r = atomicAdd(&cur[(p >> 17) & 63], 1);
        if (r < CAP) srt[r] = p & 0x1FFFFu;
    }
    __syncthreads();

    // phase 4: aggregate per node (wave w owns nodes w*16 .. w*16+15)
    int w = t >> 6, lane = t & 63;
    int h = lane >> 4;         // edge group 0..3
    int s = lane & 15;         // feats 8s..8s+7
    const uint2* fb = feats8u2 + s;

#define ACC8(U)                                                     \
    a01 += __builtin_amdgcn_cvt_pk_f32_fp8((U).x, false);           \
    a23 += __builtin_amdgcn_cvt_pk_f32_fp8((U).x, true);            \
    a45 += __builtin_amdgcn_cvt_pk_f32_fp8((U).y, false);           \
    a67 += __builtin_amdgcn_cvt_pk_f32_fp8((U).y, true);

    for (int j = 0; j < 16; ++j) {
        int nl = w * 16 + j;
        int node = b * 64 + nl;
        if (node >= N_NODES) break;
        int start = excl[nl], end = cur[nl];
        f32x2 a01 = {0.f, 0.f}, a23 = {0.f, 0.f};
        f32x2 a45 = {0.f, 0.f}, a67 = {0.f, 0.f};
        int i = start;
        for (; i + 24 <= end; i += 24) {
            uint2 uu[6];
            #pragma unroll
            for (int q = 0; q < 6; ++q)
                uu[q] = fb[(long long)srt[i + 4 * q + h] * 16];
            #pragma unroll
            for (int q = 0; q < 6; ++q) { ACC8(uu[q]); }
        }
        for (; i + 4 <= end; i += 4) {
            uint2 u = fb[(long long)srt[i + h] * 16];
            ACC8(u);
        }
        if (i + h < end) {
            uint2 u = fb[(long long)srt[i + h] * 16];
            ACC8(u);
        }
        // merge across the 4 edge-groups (lanes differing in bits 4,5)
#define MRG(A)                                                      \
        A[0] += __shfl_xor(A[0], 16, 64);                           \
        A[1] += __shfl_xor(A[1], 16, 64);                           \
        A[0] += __shfl_xor(A[0], 32, 64);                           \
        A[1] += __shfl_xor(A[1], 32, 64);
        MRG(a01) MRG(a23) MRG(a45) MRG(a67)
#undef MRG
        float ss = a01[0]*a01[0] + a01[1]*a01[1] + a23[0]*a23[0] + a23[1]*a23[1]
                 + a45[0]*a45[0] + a45[1]*a45[1] + a67[0]*a67[0] + a67[1]*a67[1];
        #pragma unroll
        for (int off = 8; off > 0; off >>= 1) ss += __shfl_xor(ss, off, 64);
        float inv = 1.0f / sqrtf(ss);
        if (h == 0) {
            union { uint4 u; _Float16 f[8]; } o;
            o.f[0] = (_Float16)(a01[0] * inv); o.f[1] = (_Float16)(a01[1] * inv);
            o.f[2] = (_Float16)(a23[0] * inv); o.f[3] = (_Float16)(a23[1] * inv);
            o.f[4] = (_Float16)(a45[0] * inv); o.f[5] = (_Float16)(a45[1] * inv);
            o.f[6] = (_Float16)(a67[0] * inv); o.f[7] = (_Float16)(a67[1] * inv);
            *reinterpret_cast<uint4*>(&h0[(long long)node * 128 + s * 8]) = o.u;
        }
    }
#undef ACC8
}

// ---------------------------------------------------------------------------
// K5: FUSED MLP, BM=96, double-buffered sB, counted-vmcnt pipeline.
// ---------------------------------------------------------------------------
__global__ __launch_bounds__(256, 2) void fused_mlp_kernel(
    const _Float16* __restrict__ h0,    // [M][128]
    const _Float16* __restrict__ WT1,   // [256][128]
    const float* __restrict__ b1,
    const _Float16* __restrict__ WT2,   // [256][256]
    const float* __restrict__ b2,
    const _Float16* __restrict__ WT3,   // [256][256]
    const float* __restrict__ b3,
    const float* __restrict__ W4,       // [256]
    float* __restrict__ partials, int M)
{
    __shared__ __align__(16) _Float16 sA[8 * 3072];      // 48 KB (8 chunks 96x32)
    __shared__ __align__(16) _Float16 sB[2][8192];       // 2 x 16 KB

    const int t = threadIdx.x;
    const int row0 = blockIdx.x * BM;

    const int ap0 = t & 3;
    const int r0 = t >> 2;
    const int ag0 = ap0 ^ ((r0 >> 1) & 3);
    int arow0 = row0 + r0; if (arow0 > M - 1) arow0 = M - 1;
    const _Float16* aSrc0 = h0 + (long long)arow0 * 128 + ag0 * 8;
    const int r1 = (256 + t) >> 2;
    const int ag1 = ap0 ^ ((r1 >> 1) & 3);
    int arow1 = row0 + r1; if (arow1 > M - 1) arow1 = M - 1;
    const _Float16* aSrc1 = h0 + (long long)arow1 * 128 + ag1 * 8;

    const int bc0 = t >> 2;
    const int gb = ap0 ^ ((bc0 >> 1) & 3);

    const int w = t >> 6, lane = t & 63;
    const int wr = w >> 1, wc = w & 1;
    const int lrow = lane & 15, g = lane >> 4;

    unsigned int offA[3], offB[8];
    #pragma unroll
    for (int rt = 0; rt < 3; ++rt) {
        int r = wr * 48 + rt * 16 + lrow;
        offA[rt] = r * 64 + (g ^ ((r >> 1) & 3)) * 16;
    }
    #pragma unroll
    for (int ct = 0; ct < 8; ++ct) {
        int cidx = wc * 128 + ct * 16 + lrow;
        offB[ct] = cidx * 64 + (g ^ ((cidx >> 1) & 3)) * 16;
    }

    float bb1[8], bb2[8], bb3[8], w4v[8];
    #pragma unroll
    for (int ct = 0; ct < 8; ++ct) {
        int col = wc * 128 + ct * 16 + lrow;
        bb1[ct] = b1[col]; bb2[ct] = b2[col];
        bb3[ct] = b3[col]; w4v[ct] = W4[col];
    }

    f32x4 acc[3][8];
    #pragma unroll
    for (int i = 0; i < 3; ++i)
        #pragma unroll
        for (int j = 0; j < 8; ++j)
            acc[i][j] = (f32x4){0.f, 0.f, 0.f, 0.f};

#define STG(WT, Kv, KC, BUF)                                                 \
    {                                                                        \
        _Pragma("unroll")                                                    \
        for (int j = 0; j < 4; ++j)                                          \
            gload16((WT) + (long long)(bc0 + j * 64) * (Kv) + gb * 8 +       \
                        (KC) * 32,                                           \
                    (char*)sB[BUF] + j * 4096 + t * 16);                     \
    }

#define WB(N)                                                                \
    asm volatile("s_waitcnt vmcnt(" #N ")" ::: "memory");                    \
    __builtin_amdgcn_s_barrier();                                            \
    __builtin_amdgcn_sched_barrier(0);

#define EB() __builtin_amdgcn_s_barrier();

#define SEAM()                                                               \
    asm volatile("s_waitcnt lgkmcnt(0)" ::: "memory");                       \
    __builtin_amdgcn_s_barrier();                                            \
    __builtin_amdgcn_sched_barrier(0);

#define STORE_ACTS(BB)                                                       \
    {                                                                        \
        _Pragma("unroll")                                                    \
        for (int ct = 0; ct < 8; ++ct) {                                     \
            int col = wc * 128 + ct * 16 + lrow;                             \
            float bb = (BB)[ct];                                             \
            int chk = col >> 5, kk = col & 31;                               \
            int kg = kk >> 3, ke = kk & 7;                                   \
            _Pragma("unroll")                                                \
            for (int rt = 0; rt < 3; ++rt) {                                 \
                _Pragma("unroll")                                            \
                for (int jj = 0; jj < 4; ++jj) {                             \
                    int rowl = wr * 48 + rt * 16 + g * 4 + jj;               \
                    int slot = kg ^ ((rowl >> 1) & 3);                       \
                    sA[chk * 3072 + rowl * 32 + slot * 8 + ke] =             \
                        (_Float16)fmaxf(acc[rt][ct][jj] + bb, 0.f);          \
                    acc[rt][ct][jj] = 0.f;                                   \
                }                                                            \
            }                                                                \
        }                                                                    \
    }

#define MFMA_CHUNK(KC, BUF)                                                  \
    {                                                                        \
        half8 a[3], bfr[8];                                                  \
        __builtin_amdgcn_s_setprio(1);                                       \
        _Pragma("unroll")                                                    \
        for (int rt = 0; rt < 3; ++rt)                                       \
            a[rt] = *reinterpret_cast<const half8*>(                         \
                (const char*)sA + (KC) * 6144 + offA[rt]);                   \
        _Pragma("unroll")                                                    \
        for (int ct = 0; ct < 8; ++ct)                                       \
            bfr[ct] = *reinterpret_cast<const half8*>(                       \
                (const char*)sB[BUF] + offB[ct]);                            \
        _Pragma("unroll")                                                    \
        for (int rt = 0; rt < 3; ++rt)                                       \
            _Pragma("unroll")                                                \
            for (int ct = 0; ct < 8; ++ct)                                   \
                acc[rt][ct] = __builtin_amdgcn_mfma_f32_16x16x32_f16(        \
                    a[rt], bfr[ct], acc[rt][ct], 0, 0, 0);                   \
        __builtin_amdgcn_s_setprio(0);                                       \
    }

    // prologue: layer-1 A chunks (96x128 f16 = 6 KB/chunk) + B chunk 0
    #pragma unroll
    for (int kc = 0; kc < 4; ++kc) {
        gload16(aSrc0 + kc * 32, (char*)sA + kc * 6144 + t * 16);
        if (t < 128)
            gload16(aSrc1 + kc * 32, (char*)sA + kc * 6144 + 4096 + t * 16);
    }
    STG(WT1, 128, 0, 0)

    // ---- pipelined chunk schedule (c = 0..19, buf = c&1) ----
    STG(WT1, 128, 1, 1)  WB(4)  MFMA_CHUNK(0, 0)  EB()   // c=0
    STG(WT1, 128, 2, 0)  WB(4)  MFMA_CHUNK(1, 1)  EB()   // c=1
    STG(WT1, 128, 3, 1)  WB(4)  MFMA_CHUNK(2, 0)  EB()   // c=2
    STG(WT2, 256, 0, 0)  WB(4)  MFMA_CHUNK(3, 1)  EB()   // c=3
    STORE_ACTS(bb1) SEAM()
    STG(WT2, 256, 1, 1)  WB(4)  MFMA_CHUNK(0, 0)  EB()   // c=4
    STG(WT2, 256, 2, 0)  WB(4)  MFMA_CHUNK(1, 1)  EB()   // c=5
    STG(WT2, 256, 3, 1)  WB(4)  MFMA_CHUNK(2, 0)  EB()   // c=6
    STG(WT2, 256, 4, 0)  WB(4)  MFMA_CHUNK(3, 1)  EB()   // c=7
    STG(WT2, 256, 5, 1)  WB(4)  MFMA_CHUNK(4, 0)  EB()   // c=8
    STG(WT2, 256, 6, 0)  WB(4)  MFMA_CHUNK(5, 1)  EB()   // c=9
    STG(WT2, 256, 7, 1)  WB(4)  MFMA_CHUNK(6, 0)  EB()   // c=10
    STG(WT3, 256, 0, 0)  WB(4)  MFMA_CHUNK(7, 1)  EB()   // c=11
    STORE_ACTS(bb2) SEAM()
    STG(WT3, 256, 1, 1)  WB(4)  MFMA_CHUNK(0, 0)  EB()   // c=12
    STG(WT3, 256, 2, 0)  WB(4)  MFMA_CHUNK(1, 1)  EB()   // c=13
    STG(WT3, 256, 3, 1)  WB(4)  MFMA_CHUNK(2, 0)  EB()   // c=14
    STG(WT3, 256, 4, 0)  WB(4)  MFMA_CHUNK(3, 1)  EB()   // c=15
    STG(WT3, 256, 5, 1)  WB(4)  MFMA_CHUNK(4, 0)  EB()   // c=16
    STG(WT3, 256, 6, 0)  WB(4)  MFMA_CHUNK(5, 1)  EB()   // c=17
    STG(WT3, 256, 7, 1)  WB(4)  MFMA_CHUNK(6, 0)  EB()   // c=18
                         WB(0)  MFMA_CHUNK(7, 1)  EB()   // c=19

    // epilogue: bias+relu, dot W4, block reduce (redf aliases sA, now dead)
    float sum = 0.f;
    #pragma unroll
    for (int ct = 0; ct < 8; ++ct) {
        float bb = bb3[ct];
        float w4 = w4v[ct];
        #pragma unroll
        for (int rt = 0; rt < 3; ++rt) {
            #pragma unroll
            for (int jj = 0; jj < 4; ++jj) {
                int row = row0 + wr * 48 + rt * 16 + g * 4 + jj;
                if (row < M) {
                    float vv = fmaxf(acc[rt][ct][jj] + bb, 0.f);
                    sum += vv * w4;
                }
            }
        }
    }
    #pragma unroll
    for (int off = 32; off > 0; off >>= 1) sum += __shfl_xor(sum, off, 64);
    float* redf = reinterpret_cast<float*>(sA);
    if (lane == 0) redf[w] = sum;
    __syncthreads();
    if (t == 0) partials[blockIdx.x] = redf[0] + redf[1] + redf[2] + redf[3];
#undef STG
#undef WB
#undef EB
#undef SEAM
#undef STORE_ACTS
#undef MFMA_CHUNK
}

// ---------------------------------------------------------------------------
// K6: final mean: out = sum(partials)/N + b4
// ---------------------------------------------------------------------------
__global__ __launch_bounds__(256) void final_kernel(
    const float* __restrict__ partials, int n,
    const float* __restrict__ b4, float* __restrict__ out)
{
    __shared__ float buf[256];
    float s = 0.f;
    for (int i = threadIdx.x; i < n; i += 256) s += partials[i];
    buf[threadIdx.x] = s;
    __syncthreads();
    for (int off = 128; off > 0; off >>= 1) {
        if (threadIdx.x < off) buf[threadIdx.x] += buf[threadIdx.x + off];
        __syncthreads();
    }
    if (threadIdx.x == 0) out[0] = buf[0] / (float)N_NODES + b4[0];
}

// ---------------------------------------------------------------------------
extern "C" void kernel_launch(void* const* d_in, const int* in_sizes, int n_in,
                              void* d_out, int out_size, void* d_ws, size_t ws_size,
                              hipStream_t stream)
{
    const float* x   = (const float*)d_in[0];
    const float* pos = (const float*)d_in[1];
    const float* z   = (const float*)d_in[2];
    const int*   ei  = (const int*)d_in[3];
    const float* W1  = (const float*)d_in[4];
    const float* b1  = (const float*)d_in[5];
    const float* W2  = (const float*)d_in[6];
    const float* b2  = (const float*)d_in[7];
    const float* W3  = (const float*)d_in[8];
    const float* b3  = (const float*)d_in[9];
    const float* W4  = (const float*)d_in[10];
    const float* b4  = (const float*)d_in[11];
    float* out = (float*)d_out;

    char* ws = (char*)d_ws;
    unsigned int* feats8   = (unsigned int*)(ws);              //  12,800,000
    _Float16*     h0       = (_Float16*)    (ws + 12800000);   //  25,600,000
    int*          gcnt     = (int*)         (ws + 38400000);   //   1,600,512
    int*          gbase    = (int*)         (ws + 40000512);   //   1,600,512
    int*          btot     = (int*)         (ws + 41601024);   //       6,252
    int*          bbase    = (int*)         (ws + 41607276);   //       6,256
    unsigned int* bucketed = (unsigned int*)(ws + 41613532);   //  12,800,000
    _Float16*     WT1      = (_Float16*)    (ws + 54413568);   //      65,536
    _Float16*     WT2      = (_Float16*)    (ws + 54479104);   //     131,072
    _Float16*     WT3      = (_Float16*)    (ws + 54610176);   //     131,072
    float*        partials = (float*)       (ws + 54741248);   //       6,252

    // prep: pack fp8 feats + weight transpose (one launch)
    {
        int total = N_NODES * 32 + 128 * 256 + 2 * 256 * 256;
        prep_kernel<<<(total + 255) / 256, 256, 0, stream>>>(
            x, pos, z, feats8, W1, WT1, W2, WT2, W3, WT3);
    }

    // CSR build via two-level bucketing (LDS int atomics only)
    coarse_hist_kernel<<<NBLK_E, 1024, 0, stream>>>(ei, gcnt);
    bucket_tot_kernel<<<NBUCK, 256, 0, stream>>>(gcnt, btot);
    scan_buckets_kernel<<<1, 1024, 0, stream>>>(btot, bbase);
    colscan_kernel<<<NBUCK, 256, 0, stream>>>(gcnt, bbase, gbase);
    bucket_scatter_kernel<<<NBLK_E, 1024, 0, stream>>>(ei, gcnt, gbase, bucketed);

    // per-bucket counting sort + fp8 aggregate (uint2/16-lane) -> h0 (f16)
    sortagg_kernel<<<NBUCK, 256, 0, stream>>>(
        bbase, bucketed, (const uint2*)feats8, h0);

    // fused MLP (3 layers + W4 dot), BM=96 counted-vmcnt pipeline -> partials
    fused_mlp_kernel<<<MLP_BLOCKS, 256, 0, stream>>>(
        h0, WT1, b1, WT2, b2, WT3, b3, W4, partials, N_NODES);

    // final mean
    final_kernel<<<1, 256, 0, stream>>>(partials, MLP_BLOCKS, b4, out);
}